// Round 19
// baseline (165.288 us; speedup 1.0000x reference)
//
#include <hip/hip_runtime.h>
#include <hip/hip_fp16.h>
#include <math.h>

#define NODE_DIM 64
#define EDGE_DIM 16
#define CAP 64
#define NEG_SLOPE 0.2f
#define BN_EPS 1e-5f

typedef unsigned short ushort_t;
typedef unsigned int uint_t;
typedef __fp16 h2_t __attribute__((ext_vector_type(2)));

template<int CTRL>
__device__ __forceinline__ float dpp_mov_f(float v) {
    return __int_as_float(__builtin_amdgcn_update_dpp(
        0, __float_as_int(v), CTRL, 0xF, 0xF, true));
}
// full-row (16-lane) sum, result in all lanes of each row
__device__ __forceinline__ float row_sum16(float v) {
    v += dpp_mov_f<0x128>(v);   // row_ror:8
    v += dpp_mov_f<0x124>(v);   // row_ror:4
    v += dpp_mov_f<0x122>(v);   // row_ror:2
    v += dpp_mov_f<0x121>(v);   // row_ror:1
    return v;
}
__device__ __forceinline__ float wave_sum64(float v) {
    v = row_sum16(v);
    v += __shfl_xor(v, 16, 64);
    v += __shfl_xor(v, 32, 64);
    return v;
}
__device__ __forceinline__ float wave_max64(float v) {
    v = fmaxf(v, dpp_mov_f<0x128>(v));
    v = fmaxf(v, dpp_mov_f<0x124>(v));
    v = fmaxf(v, dpp_mov_f<0x122>(v));
    v = fmaxf(v, dpp_mov_f<0x121>(v));
    v = fmaxf(v, __shfl_xor(v, 16, 64));
    v = fmaxf(v, __shfl_xor(v, 32, 64));
    return v;
}
__device__ __forceinline__ ushort_t f2bf(float f) {  // round-to-nearest-even
    unsigned int b = __float_as_uint(f);
    b += 0x7FFFu + ((b >> 16) & 1u);
    return (ushort_t)(b >> 16);
}
__device__ __forceinline__ float bf2f(ushort_t u) {
    return __uint_as_float(((unsigned int)u) << 16);
}
__device__ __forceinline__ uint_t packh2(float a, float b) {
    __half2 h;
    h.x = __float2half_rn(a);
    h.y = __float2half_rn(b);
    return *reinterpret_cast<uint_t*>(&h);
}
__device__ __forceinline__ float2 unpackh2(uint_t u) {
    __half2 h = *reinterpret_cast<__half2*>(&u);
    return make_float2(__half2float(h.x), __half2float(h.y));
}
__device__ __forceinline__ float fdot2u(uint_t a, uint_t b, float c) {
#if __has_builtin(__builtin_amdgcn_fdot2)
    union { uint_t u; h2_t h; } ua, ub;
    ua.u = a; ub.u = b;
    return __builtin_amdgcn_fdot2(ua.h, ub.h, c, false);
#else
    float2 fa = unpackh2(a), fb = unpackh2(b);
    return fmaf(fa.y, fb.y, fmaf(fa.x, fb.x, c));
#endif
}

// K1: xlbf = bf16(x@Wl+bl) ; xrbf = bf16(x@Wr+br). One wave per row.
// Weights as f16-pair column regs; x via wave-uniform float4 broadcasts.
// ZERO LDS, zero DS ops.
__global__ __launch_bounds__(256) void k_transform(
    const float* __restrict__ x, const float* __restrict__ Wl,
    const float* __restrict__ bl, const float* __restrict__ Wr,
    const float* __restrict__ br, ushort_t* __restrict__ xlbf,
    ushort_t* __restrict__ xrbf, int n)
{
    int lane = threadIdx.x & 63;
    int wid = threadIdx.x >> 6;

    uint_t wlp[32], wrp[32];
#pragma unroll
    for (int m = 0; m < 32; m++) {
        wlp[m] = packh2(Wl[(2 * m) * NODE_DIM + lane],
                        Wl[(2 * m + 1) * NODE_DIM + lane]);
        wrp[m] = packh2(Wr[(2 * m) * NODE_DIM + lane],
                        Wr[(2 * m + 1) * NODE_DIM + lane]);
    }
    float blc = bl[lane], brc = br[lane];

    for (int row = blockIdx.x * 4 + wid; row < n; row += gridDim.x * 4) {
        const float4* x4 = (const float4*)(x + (size_t)row * NODE_DIM);
        float al = blc, ar = brc;
#pragma unroll
        for (int p = 0; p < 16; p++) {
            float4 v = x4[p];    // wave-uniform broadcast, L1-served
            uint_t x01 = packh2(v.x, v.y);
            uint_t x23 = packh2(v.z, v.w);
            al = fdot2u(x01, wlp[2 * p], al);
            al = fdot2u(x23, wlp[2 * p + 1], al);
            ar = fdot2u(x01, wrp[2 * p], ar);
            ar = fdot2u(x23, wrp[2 * p + 1], ar);
        }
        xlbf[(size_t)row * NODE_DIM + lane] = f2bf(al);
        xrbf[(size_t)row * NODE_DIM + lane] = f2bf(ar);
    }
}

// K2: edge-parallel logits. Wave = 64 consecutive edges, lane = channel.
// eattr staged to LDS as f16 pairs; eproj via 8 v_dot2; 8-deep pipe on
// xl/xr row gathers; logit reduce via DPP; fast path keeps logits in
// REGISTERS (kp[4], static idx via full unroll) + 4x4 shfl transpose —
// zero slg DS traffic. 16B payload written at CAP-strided CSR slot.
__global__ __launch_bounds__(256) void k_edge(
    const int* __restrict__ ei, const float* __restrict__ eattr,
    const float* __restrict__ We, const float* __restrict__ att,
    int* __restrict__ cursors,
    const ushort_t* __restrict__ xlbf, const ushort_t* __restrict__ xrbf,
    uint4* __restrict__ payload, int E)
{
    __shared__ uint_t sea[4][64 * 8];   // per-wave eattr rows, f16 pairs (2KB)
    __shared__ float slg[4][64 * 4];    // tail path only

    int lane = threadIdx.x & 63;
    int wid = threadIdx.x >> 6;
    int wbase = (blockIdx.x * 4 + wid) * 64;
    if (wbase >= E) return;
    wbase = __builtin_amdgcn_readfirstlane(wbase);
    int cnt = E - wbase; if (cnt > 64) cnt = 64;

    // stage eattr rows -> packed f16 pairs: coalesced burst + cvt
    {
        const float4* esrc = (const float4*)(eattr + (size_t)wbase * EDGE_DIM);
        uint2* sdst = (uint2*)sea[wid];
        int lim = cnt * 4;
#pragma unroll
        for (int r = 0; r < 4; r++) {
            int idx = r * 64 + lane;
            if (idx < lim) {
                float4 v = esrc[idx];
                sdst[idx] = make_uint2(packh2(v.x, v.y), packh2(v.z, v.w));
            }
        }
    }

    // per-lane We column as f16 pairs
    uint_t wep[8];
#pragma unroll
    for (int m = 0; m < 8; m++)
        wep[m] = packh2(We[(2 * m) * NODE_DIM + lane],
                        We[(2 * m + 1) * NODE_DIM + lane]);
    float att_p = att[lane];
    float att_n = att_p * NEG_SLOPE;

    // per-lane edge bookkeeping (atomic early; result used only at the end)
    int src_l = 0, pos_l = CAP, dst_l = 0;
    if (lane < cnt) {
        src_l = ei[wbase + lane];
        dst_l = ei[E + wbase + lane];
        pos_l = atomicAdd(&cursors[dst_l], 1);
    }
    int dst_l_bc = dst_l;

    uint_t* seaW = sea[wid];

    ushort_t pxl[8], pxr[8];
    auto LOADT = [&](int t, int k) {   // t uniform, k compile-time
        int s = __builtin_amdgcn_readlane(src_l, t);
        int d = __builtin_amdgcn_readlane(dst_l_bc, t);
        pxl[k] = xlbf[(size_t)s * NODE_DIM + lane];
        pxr[k] = xrbf[(size_t)d * NODE_DIM + lane];
    };
    auto LOGIT = [&](int t, int k) -> float {
        const uint4* e4 = (const uint4*)(seaW + t * 8);
        uint4 ea0 = e4[0], ea1 = e4[1];   // 2x ds_read_b128
        float p0 = 0.f, p1 = 0.f;
        p0 = fdot2u(ea0.x, wep[0], p0);  p1 = fdot2u(ea0.y, wep[1], p1);
        p0 = fdot2u(ea0.z, wep[2], p0);  p1 = fdot2u(ea0.w, wep[3], p1);
        p0 = fdot2u(ea1.x, wep[4], p0);  p1 = fdot2u(ea1.y, wep[5], p1);
        p0 = fdot2u(ea1.z, wep[6], p0);  p1 = fdot2u(ea1.w, wep[7], p1);
        float sv = bf2f(pxl[k]) + bf2f(pxr[k]) + (p0 + p1);
        float g = sv * (sv > 0.f ? att_p : att_n);   // lrelu * att
        return row_sum16(g);                         // DPP, no DS pipe
    };

    if (cnt == 64) {
        // fast path (E % 64 == 0 -> always taken): fully unrolled so kp[]
        // has static indices; 8-deep pipe on gathers; zero logit DS traffic.
        float kp[4];
#pragma unroll
        for (int k = 0; k < 8; k++) LOADT(k, k);
#pragma unroll
        for (int t = 0; t < 64; t++) {
            float g = LOGIT(t, t & 7);
            if ((lane & 15) == (t & 15)) kp[t >> 4] = g;
            if (t + 8 < 64) LOADT(t + 8, (t + 8) & 7);
        }
        // 4x4 register transpose: kp[j] = G(16j+m, h4) -> B[j] = G(lane, j)
        int h4 = lane >> 4;
        float xA = (h4 & 1) ? kp[0] : kp[1];
        float yA = (h4 & 1) ? kp[2] : kp[3];
        xA = __shfl_xor(xA, 16, 64);
        yA = __shfl_xor(yA, 16, 64);
        float A0 = (h4 & 1) ? xA : kp[0];
        float A1 = (h4 & 1) ? kp[1] : xA;
        float A2 = (h4 & 1) ? yA : kp[2];
        float A3 = (h4 & 1) ? kp[3] : yA;
        float xB = (h4 & 2) ? A0 : A2;
        float yB = (h4 & 2) ? A1 : A3;
        xB = __shfl_xor(xB, 32, 64);
        yB = __shfl_xor(yB, 32, 64);
        float B0 = (h4 & 2) ? xB : A0;
        float B1 = (h4 & 2) ? yB : A1;
        float B2 = (h4 & 2) ? A2 : xB;
        float B3 = (h4 & 2) ? A3 : yB;
        if (pos_l < CAP)
            payload[(size_t)dst_l * CAP + pos_l] =
                make_uint4((uint_t)src_l, packh2(B0, B1), packh2(B2, B3), 0u);
    } else {
        // tail (never taken when E % 64 == 0): guarded loop via LDS
        float* slgW = slg[wid];
        for (int t = 0; t < cnt; t++) {
            int s = __builtin_amdgcn_readlane(src_l, t);
            int d = __builtin_amdgcn_readlane(dst_l_bc, t);
            pxl[0] = xlbf[(size_t)s * NODE_DIM + lane];
            pxr[0] = xrbf[(size_t)d * NODE_DIM + lane];
            float g = LOGIT(t, 0);
            if ((lane & 15) == 0) slgW[t * 4 + (lane >> 4)] = g;
        }
        __builtin_amdgcn_s_waitcnt(0);  // drain lgkm before readback
        if (lane < cnt && pos_l < CAP) {
            float4 lg4 = ((const float4*)slgW)[lane];
            payload[(size_t)dst_l * CAP + pos_l] =
                make_uint4((uint_t)src_l, packh2(lg4.x, lg4.y),
                           packh2(lg4.z, lg4.w), 0u);
        }
    }
}

// K3 (fused): 4 nodes/block, one wave each. COALESCED payload read (no
// indirection) + wave softmax (lane = edge slot), then TRANSPOSED phase C:
// lane = (row r, chunk c); all gather batches prefetched upfront (single
// latency exposure); DPP+shfl cross-group reduce.
__global__ __launch_bounds__(256) void k_fused(
    const uint4* __restrict__ payload, const int* __restrict__ cursors,
    const ushort_t* __restrict__ xlbf, const float* __restrict__ bias,
    float* __restrict__ out, int n)
{
    __shared__ float salpha[4][CAP * 4];
    __shared__ int ssrc[4][CAP];

    int wid = threadIdx.x >> 6;
    int lane = threadIdx.x & 63;
    int i = blockIdx.x * 4 + wid;
    if (i >= n) return;

    int deg = cursors[i];
    if (deg > CAP) deg = CAP;
    bool act = (lane < deg);

    uint4 pl = act ? payload[(size_t)i * CAP + lane] : make_uint4(0u, 0u, 0u, 0u);
    int se_x = (int)pl.x;
    float2 g01 = unpackh2(pl.y);
    float2 g23 = unpackh2(pl.z);

    float l0 = act ? g01.x : -1e30f;
    float l1 = act ? g01.y : -1e30f;
    float l2 = act ? g23.x : -1e30f;
    float l3 = act ? g23.y : -1e30f;
    float m0 = wave_max64(l0), m1 = wave_max64(l1);
    float m2 = wave_max64(l2), m3 = wave_max64(l3);
    float e0 = act ? __expf(l0 - m0) : 0.f;
    float e1 = act ? __expf(l1 - m1) : 0.f;
    float e2 = act ? __expf(l2 - m2) : 0.f;
    float e3 = act ? __expf(l3 - m3) : 0.f;
    float s0 = wave_sum64(e0), s1 = wave_sum64(e1);
    float s2 = wave_sum64(e2), s3 = wave_sum64(e3);
    float* salW = salpha[wid];
    int* ssrcW = ssrc[wid];
    // all 64 lane-slots written; inactive lanes have alpha = 0, src = 0
    ((float4*)salW)[lane] = make_float4(
        e0 / (s0 + 1e-16f), e1 / (s1 + 1e-16f),
        e2 / (s2 + 1e-16f), e3 / (s3 + 1e-16f));
    ssrcW[lane] = se_x;

    // phase C (transposed): lane = (r = lane>>3, c = lane&7)
    int r = lane >> 3, c = lane & 7;
    float a0 = 0.f, a1 = 0.f, a2 = 0.f, a3 = 0.f;
    float a4 = 0.f, a5 = 0.f, a6 = 0.f, a7 = 0.f;
    int nb = (deg + 7) >> 3;   // wave-uniform, <= 8

    uint4 v0, v1, v2, v3, v4, v5, v6, v7;
#define LDV(B, V)                                                        \
    if ((B) < nb) {                                                      \
        int st = ssrcW[(B) * 8 + r];                                     \
        V = *(const uint4*)(xlbf + (size_t)st * NODE_DIM + c * 8);       \
    }
    // issue ALL gathers upfront: single latency exposure
    LDV(0, v0) LDV(1, v1) LDV(2, v2) LDV(3, v3)
    LDV(4, v4) LDV(5, v5) LDV(6, v6) LDV(7, v7)
#undef LDV

#define ACC(B, V)                                                        \
    if ((B) < nb) {                                                      \
        float al = salW[((B) * 8 + r) * 4 + (c >> 1)];                   \
        a0 = fmaf(al, __uint_as_float(V.x << 16), a0);                   \
        a1 = fmaf(al, __uint_as_float(V.x & 0xFFFF0000u), a1);           \
        a2 = fmaf(al, __uint_as_float(V.y << 16), a2);                   \
        a3 = fmaf(al, __uint_as_float(V.y & 0xFFFF0000u), a3);           \
        a4 = fmaf(al, __uint_as_float(V.z << 16), a4);                   \
        a5 = fmaf(al, __uint_as_float(V.z & 0xFFFF0000u), a5);           \
        a6 = fmaf(al, __uint_as_float(V.w << 16), a6);                   \
        a7 = fmaf(al, __uint_as_float(V.w & 0xFFFF0000u), a7);           \
    }
    ACC(0, v0) ACC(1, v1) ACC(2, v2) ACC(3, v3)
    ACC(4, v4) ACC(5, v5) ACC(6, v6) ACC(7, v7)
#undef ACC

    // reduce across the 8 r-groups: xor8 (DPP ror8 within row16) + shfl 16,32
#define RED(x) do { \
        x += dpp_mov_f<0x128>(x); \
        x += __shfl_xor(x, 16, 64); \
        x += __shfl_xor(x, 32, 64); } while (0)
    RED(a0); RED(a1); RED(a2); RED(a3);
    RED(a4); RED(a5); RED(a6); RED(a7);
#undef RED
    // lane stores channel 8c + r: static select tree on r
    float t0 = (r & 1) ? a1 : a0;
    float t1 = (r & 1) ? a3 : a2;
    float t2 = (r & 1) ? a5 : a4;
    float t3 = (r & 1) ? a7 : a6;
    float u0 = (r & 2) ? t1 : t0;
    float u1 = (r & 2) ? t3 : t2;
    float w  = (r & 4) ? u1 : u0;
    int ch = c * 8 + r;
    out[(size_t)i * NODE_DIM + ch] = w + bias[ch];
}

// K4: column sums / sumsq for BatchNorm
__global__ __launch_bounds__(256) void k_bnstat(
    const float* __restrict__ out, float* __restrict__ stats, int n)
{
    __shared__ float sbuf[256];
    int col = threadIdx.x & 63;
    int rgrp = threadIdx.x >> 6;
    float s = 0.f, q = 0.f;
    for (int row = blockIdx.x * 4 + rgrp; row < n; row += gridDim.x * 4) {
        float v = out[(size_t)row * 64 + col];
        s += v;
        q = fmaf(v, v, q);
    }
    sbuf[threadIdx.x] = s;
    __syncthreads();
    if (threadIdx.x < 64) {
        s = sbuf[threadIdx.x] + sbuf[threadIdx.x + 64] +
            sbuf[threadIdx.x + 128] + sbuf[threadIdx.x + 192];
        atomicAdd(&stats[col], s);
    }
    __syncthreads();
    sbuf[threadIdx.x] = q;
    __syncthreads();
    if (threadIdx.x < 64) {
        q = sbuf[threadIdx.x] + sbuf[threadIdx.x + 64] +
            sbuf[threadIdx.x + 128] + sbuf[threadIdx.x + 192];
        atomicAdd(&stats[64 + col], q);
    }
}

// K5: BN normalize + residual + exact GELU, in place on d_out
__global__ __launch_bounds__(256) void k_final(
    float* __restrict__ out, const float* __restrict__ x,
    const float* __restrict__ stats, const float* __restrict__ gamma,
    const float* __restrict__ beta, int total, float invn)
{
    int i = blockIdx.x * 256 + threadIdx.x;
    if (i >= total) return;
    int c = i & 63;
    float mean = stats[c] * invn;
    float var = stats[64 + c] * invn - mean * mean;
    float z = (out[i] - mean) * rsqrtf(var + BN_EPS) * gamma[c] + beta[c] + x[i];
    out[i] = z * 0.5f * (1.f + erff(z * 0.70710678118654752f));
}

extern "C" void kernel_launch(void* const* d_in, const int* in_sizes, int n_in,
                              void* d_out, int out_size, void* d_ws, size_t ws_size,
                              hipStream_t stream)
{
    const float* x     = (const float*)d_in[0];
    const int*   ei    = (const int*)d_in[1];
    const float* eattr = (const float*)d_in[2];
    const float* Wl    = (const float*)d_in[3];
    const float* bl    = (const float*)d_in[4];
    const float* Wr    = (const float*)d_in[5];
    const float* br    = (const float*)d_in[6];
    const float* We    = (const float*)d_in[7];
    const float* att   = (const float*)d_in[8];
    const float* bias  = (const float*)d_in[9];
    const float* gamma = (const float*)d_in[10];
    const float* beta  = (const float*)d_in[11];
    int n = in_sizes[0] / NODE_DIM;
    int E = in_sizes[1] / 2;

    char* ws = (char*)d_ws;
    ushort_t* xlbf    = (ushort_t*)ws; ws += (size_t)n * NODE_DIM * 2;
    ushort_t* xrbf    = (ushort_t*)ws; ws += (size_t)n * NODE_DIM * 2;
    uint4*    payload = (uint4*)ws;    ws += (size_t)n * CAP * 16;
    int*      cursors = (int*)ws;      ws += (size_t)n * 4;
    float*    stats   = (float*)ws;    ws += 128 * 4;

    // zero cursors + stats (contiguous)
    hipMemsetAsync(cursors, 0, (size_t)(n + 128) * 4, stream);

    k_transform<<<1024, 256, 0, stream>>>(x, Wl, bl, Wr, br, xlbf, xrbf, n);
    k_edge<<<(E + 255) / 256, 256, 0, stream>>>(
        ei, eattr, We, att, cursors, xlbf, xrbf, payload, E);
    k_fused<<<(n + 3) / 4, 256, 0, stream>>>(
        payload, cursors, xlbf, bias, (float*)d_out, n);
    k_bnstat<<<256, 256, 0, stream>>>((const float*)d_out, stats, n);
    k_final<<<(n * NODE_DIM + 255) / 256, 256, 0, stream>>>(
        (float*)d_out, x, stats, gamma, beta, n * NODE_DIM, 1.0f / n);
}